// Round 20
// baseline (302.651 us; speedup 1.0000x reference)
//
#include <hip/hip_runtime.h>
#include <stdint.h>

typedef __attribute__((ext_vector_type(8))) short short8;
typedef __attribute__((ext_vector_type(8))) unsigned short ushort8;
typedef __attribute__((ext_vector_type(4))) float f32x4;

__device__ __forceinline__ ushort f2bf(float f) {
  union { float f; uint32_t u; } v; v.f = f;
  uint32_t r = v.u + 0x7FFFu + ((v.u >> 16) & 1u);
  return (ushort)(r >> 16);
}

__device__ __forceinline__ ushort f2bf_trunc(float f) {  // round-to-zero, 1 op
  union { float f; uint32_t u; } v; v.f = f;
  return (ushort)(v.u >> 16);
}

__device__ __forceinline__ float fexp2(float x) {  // 2^x, single v_exp_f32
  float r;
  asm("v_exp_f32 %0, %1" : "=v"(r) : "v"(x));
  return r;
}

__device__ __forceinline__ void gld16(const ushort* g, ushort* l) {
  __builtin_amdgcn_global_load_lds((const __attribute__((address_space(1))) void*)g,
                                   (__attribute__((address_space(3))) void*)l, 16, 0, 0);
}

// ---------------- fp32 -> bf16 elementwise ----------------
__global__ __launch_bounds__(256) void k_f32_to_bf16(const float* __restrict__ in,
                                                     ushort* __restrict__ out, long n) {
  long i = ((long)blockIdx.x * 256 + threadIdx.x) * 8;
  if (i >= n) return;
  float4 a = *(const float4*)(in + i);
  float4 b = *(const float4*)(in + i + 4);
  ushort8 o;
  o[0] = f2bf(a.x); o[1] = f2bf(a.y); o[2] = f2bf(a.z); o[3] = f2bf(a.w);
  o[4] = f2bf(b.x); o[5] = f2bf(b.y); o[6] = f2bf(b.z); o[7] = f2bf(b.w);
  *(ushort8*)(out + i) = o;
}

// ---------------- fp32 (R x C) -> bf16 transposed (C x R), out row-stride R ----------------
__global__ __launch_bounds__(256) void k_w_transpose(const float* __restrict__ in,
                                                     ushort* __restrict__ out, int R, int C) {
  __shared__ float t[32][33];
  int tx = threadIdx.x & 31, ty = threadIdx.x >> 5;
  int r0 = blockIdx.y * 32, c0 = blockIdx.x * 32;
#pragma unroll
  for (int i = 0; i < 4; i++)
    t[ty + i * 8][tx] = in[(size_t)(r0 + ty + i * 8) * C + c0 + tx];
  __syncthreads();
#pragma unroll
  for (int i = 0; i < 4; i++)
    out[(size_t)(c0 + ty + i * 8) * R + r0 + tx] = f2bf(t[tx][ty + i * 8]);
}

// ---------------- V slice of QKV (B,T,3072) -> VT (B,G,HD,T) bf16 ----------------
__global__ __launch_bounds__(256) void k_v_transpose(const ushort* __restrict__ qkv,
                                                     ushort* __restrict__ out) {
  __shared__ ushort t[32][33];
  int tx = threadIdx.x & 31, ty = threadIdx.x >> 5;
  int t0 = blockIdx.x * 32, d0 = blockIdx.y * 32;
  int b = blockIdx.z >> 2, g = blockIdx.z & 3;
#pragma unroll
  for (int i = 0; i < 4; i++)
    t[ty + i * 8][tx] =
        qkv[((size_t)b * 2048 + t0 + ty + i * 8) * 3072 + 2560 + g * 128 + d0 + tx];
  __syncthreads();
#pragma unroll
  for (int i = 0; i < 4; i++)
    out[(((size_t)b * 4 + g) * 128 + d0 + ty + i * 8) * 2048 + t0 + tx] = t[tx][ty + i * 8];
}

// A-half h (128 rows, 16KB) of K-tile t -> slot; 2 gld16/thread.
__device__ __forceinline__ void stageA_half(const ushort* Atile, int K, int t,
                                            ushort* slot, int h, int tid) {
#pragma unroll
  for (int n = 0; n < 2; n++) {
    int row = h * 128 + n * 64 + (tid >> 3);
    int c0 = (tid & 7) * 8;
    int cs = c0 ^ ((row & 7) << 3);
    gld16(Atile + (size_t)row * K + t * 64 + cs, slot + row * 64 + c0);
  }
}

// B chunk bq (64 rows, 8KB) of K-tile t -> slot; 1 gld16/thread.
__device__ __forceinline__ void stageB_third(const ushort* Btile, int K, int t,
                                             ushort* slot, int b, int tid) {
  int row = b * 64 + (tid >> 3);
  int c0 = (tid & 7) * 8;
  int cs = c0 ^ ((row & 7) << 3);
  gld16(Btile + (size_t)row * K + t * 64 + cs, slot + row * 64 + c0);
}

// ---------------- QKV GEMM: 256x192, BK=64, 4-phase pipelined ----------
// (byte-identical to R16/R18/R19's verified k_gemm192p: 120.5us, 512 blocks)
__global__ __launch_bounds__(512) void k_gemm192p(const ushort* __restrict__ A,
                                                  const ushort* __restrict__ BT,
                                                  ushort* __restrict__ C, int M, int N, int K) {
  __shared__ ushort As[3][16384];  // 3 x 256x64
  __shared__ ushort Bs[2][12288];  // 2 x 192x64
  const int tid = threadIdx.x;
  const int lane = tid & 63, wid = tid >> 6;
  const int wm = wid >> 2, wn = wid & 3;
  const int l15 = lane & 15, l4 = lane >> 4;
  const int rsw = (l15 & 7) << 3;
  int nwg = gridDim.x * gridDim.y;
  int lin = blockIdx.y * gridDim.x + blockIdx.x;
  int swz = (lin & 7) * (nwg >> 3) + (lin >> 3);
  int bx = swz % gridDim.x, by = swz / gridDim.x;
  const int m0 = by * 256, n0 = bx * 192;
  const ushort* Atile = A + (size_t)m0 * K;
  const ushort* Btile = BT + (size_t)n0 * K;
  const int NK = K >> 6;

  f32x4 acc[8][3] = {};

  stageA_half(Atile, K, 0, As[0], 0, tid);
  stageA_half(Atile, K, 0, As[0], 1, tid);
  stageB_third(Btile, K, 0, Bs[0], 0, tid);
  stageB_third(Btile, K, 0, Bs[0], 1, tid);
  stageB_third(Btile, K, 0, Bs[0], 2, tid);
  stageA_half(Atile, K, 1, As[1], 0, tid);
  stageA_half(Atile, K, 1, As[1], 1, tid);
  stageB_third(Btile, K, 1, Bs[1], 0, tid);
  stageB_third(Btile, K, 1, Bs[1], 1, tid);
  stageB_third(Btile, K, 1, Bs[1], 2, tid);
  asm volatile("s_waitcnt vmcnt(7)" ::: "memory");
  asm volatile("s_barrier" ::: "memory");

#pragma unroll 1
  for (int t = 0; t < NK; ++t) {
    const ushort* Ab = As[t % 3];
    const ushort* Bb = Bs[t & 1];
    ushort* An = As[(t + 2) % 3];
    ushort* Bn = Bs[t & 1];
    const bool st = (t + 2 < NK);
    short8 bfrag[3][2];

#pragma unroll
    for (int nf = 0; nf < 3; nf++)
#pragma unroll
      for (int ks = 0; ks < 2; ks++)
        bfrag[nf][ks] = *(const short8*)&Bb[(wn * 48 + nf * 16 + l15) * 64 +
                                            ((ks * 32 + l4 * 8) ^ rsw)];
    {
      short8 afr[2][2];
#pragma unroll
      for (int dm = 0; dm < 2; dm++)
#pragma unroll
        for (int ks = 0; ks < 2; ks++)
          afr[dm][ks] = *(const short8*)&Ab[(wm * 128 + dm * 16 + l15) * 64 +
                                            ((ks * 32 + l4 * 8) ^ rsw)];
      if (st) stageA_half(Atile, K, t + 2, An, 0, tid);
      asm volatile("s_barrier" ::: "memory");
      __builtin_amdgcn_s_setprio(1);
#pragma unroll
      for (int dm = 0; dm < 2; dm++)
#pragma unroll
        for (int nf = 0; nf < 3; nf++)
#pragma unroll
          for (int ks = 0; ks < 2; ks++)
            acc[dm][nf] = __builtin_amdgcn_mfma_f32_16x16x32_bf16(
                afr[dm][ks], bfrag[nf][ks], acc[dm][nf], 0, 0, 0);
      __builtin_amdgcn_s_setprio(0);
      asm volatile("s_barrier" ::: "memory");
    }
#pragma unroll
    for (int q = 1; q < 4; q++) {
      short8 afr[2][2];
#pragma unroll
      for (int dm = 0; dm < 2; dm++)
#pragma unroll
        for (int ks = 0; ks < 2; ks++)
          afr[dm][ks] = *(const short8*)&Ab[(wm * 128 + (q * 2 + dm) * 16 + l15) * 64 +
                                            ((ks * 32 + l4 * 8) ^ rsw)];
      if (st) {
        if (q == 1) stageB_third(Btile, K, t + 2, Bn, 0, tid);
        if (q == 2) stageB_third(Btile, K, t + 2, Bn, 1, tid);
        if (q == 3) {
          stageA_half(Atile, K, t + 2, An, 1, tid);
          stageB_third(Btile, K, t + 2, Bn, 2, tid);
        }
      }
      asm volatile("s_barrier" ::: "memory");
      __builtin_amdgcn_s_setprio(1);
#pragma unroll
      for (int dm = 0; dm < 2; dm++)
#pragma unroll
        for (int nf = 0; nf < 3; nf++)
#pragma unroll
          for (int ks = 0; ks < 2; ks++)
            acc[q * 2 + dm][nf] = __builtin_amdgcn_mfma_f32_16x16x32_bf16(
                afr[dm][ks], bfrag[nf][ks], acc[q * 2 + dm][nf], 0, 0, 0);
      __builtin_amdgcn_s_setprio(0);
      if (q < 3) {
        asm volatile("s_barrier" ::: "memory");
      } else {
        if (st) asm volatile("s_waitcnt vmcnt(7)" ::: "memory");
        else    asm volatile("s_waitcnt vmcnt(0)" ::: "memory");
        asm volatile("s_barrier" ::: "memory");
      }
    }
  }

#pragma unroll
  for (int mf = 0; mf < 8; mf++)
#pragma unroll
    for (int nf = 0; nf < 3; nf++)
#pragma unroll
      for (int r = 0; r < 4; r++) {
        int m = m0 + wm * 128 + mf * 16 + l4 * 4 + r;
        int n = n0 + wn * 48 + nf * 16 + l15;
        C[(size_t)m * N + n] = f2bf(acc[mf][nf][r]);
      }
}

// ---------------- WO GEMM: 256x256, BK=64, 4-phase pipelined ----------
// (byte-identical to R19's verified k_gemm256p4: ~67us, 160KB LDS, 1 full round)
__global__ __launch_bounds__(512) void k_gemm256p4(const ushort* __restrict__ A,
                                                   const ushort* __restrict__ BT,
                                                   float* __restrict__ C, int M, int N, int K) {
  __shared__ ushort As[3][16384];  // 3 x 256x64 = 96KB
  __shared__ ushort Bs[2][16384];  // 2 x 256x64 = 64KB
  const int tid = threadIdx.x;
  const int lane = tid & 63, wid = tid >> 6;
  const int wm = wid >> 2, wn = wid & 3;
  const int l15 = lane & 15, l4 = lane >> 4;
  const int rsw = (l15 & 7) << 3;
  int nwg = gridDim.x * gridDim.y;
  int lin = blockIdx.y * gridDim.x + blockIdx.x;
  int swz = (lin & 7) * (nwg >> 3) + (lin >> 3);
  int bx = swz % gridDim.x, by = swz / gridDim.x;
  const int m0 = by * 256, n0 = bx * 256;
  const ushort* Atile = A + (size_t)m0 * K;
  const ushort* Btile = BT + (size_t)n0 * K;
  const int NK = K >> 6;

  f32x4 acc[8][4] = {};

  stageA_half(Atile, K, 0, As[0], 0, tid);
  stageA_half(Atile, K, 0, As[0], 1, tid);
  stageB_third(Btile, K, 0, Bs[0], 0, tid);
  stageB_third(Btile, K, 0, Bs[0], 1, tid);
  stageB_third(Btile, K, 0, Bs[0], 2, tid);
  stageB_third(Btile, K, 0, Bs[0], 3, tid);
  stageA_half(Atile, K, 1, As[1], 0, tid);
  stageA_half(Atile, K, 1, As[1], 1, tid);
  stageB_third(Btile, K, 1, Bs[1], 0, tid);
  stageB_third(Btile, K, 1, Bs[1], 1, tid);
  stageB_third(Btile, K, 1, Bs[1], 2, tid);
  stageB_third(Btile, K, 1, Bs[1], 3, tid);
  asm volatile("s_waitcnt vmcnt(8)" ::: "memory");
  asm volatile("s_barrier" ::: "memory");

#pragma unroll 1
  for (int t = 0; t < NK; ++t) {
    const ushort* Ab = As[t % 3];
    const ushort* Bb = Bs[t & 1];
    ushort* An = As[(t + 2) % 3];
    ushort* Bn = Bs[t & 1];
    const bool st = (t + 2 < NK);
    short8 bfrag[4][2];

#pragma unroll
    for (int nf = 0; nf < 4; nf++)
#pragma unroll
      for (int ks = 0; ks < 2; ks++)
        bfrag[nf][ks] = *(const short8*)&Bb[(wn * 64 + nf * 16 + l15) * 64 +
                                            ((ks * 32 + l4 * 8) ^ rsw)];
    {
      short8 afr[2][2];
#pragma unroll
      for (int dm = 0; dm < 2; dm++)
#pragma unroll
        for (int ks = 0; ks < 2; ks++)
          afr[dm][ks] = *(const short8*)&Ab[(wm * 128 + dm * 16 + l15) * 64 +
                                            ((ks * 32 + l4 * 8) ^ rsw)];
      if (st) stageA_half(Atile, K, t + 2, An, 0, tid);
      asm volatile("s_barrier" ::: "memory");
      __builtin_amdgcn_s_setprio(1);
#pragma unroll
      for (int dm = 0; dm < 2; dm++)
#pragma unroll
        for (int nf = 0; nf < 4; nf++)
#pragma unroll
          for (int ks = 0; ks < 2; ks++)
            acc[dm][nf] = __builtin_amdgcn_mfma_f32_16x16x32_bf16(
                afr[dm][ks], bfrag[nf][ks], acc[dm][nf], 0, 0, 0);
      __builtin_amdgcn_s_setprio(0);
      asm volatile("s_barrier" ::: "memory");
    }
#pragma unroll
    for (int q = 1; q < 4; q++) {
      short8 afr[2][2];
#pragma unroll
      for (int dm = 0; dm < 2; dm++)
#pragma unroll
        for (int ks = 0; ks < 2; ks++)
          afr[dm][ks] = *(const short8*)&Ab[(wm * 128 + (q * 2 + dm) * 16 + l15) * 64 +
                                            ((ks * 32 + l4 * 8) ^ rsw)];
      if (st) {
        if (q == 1) stageB_third(Btile, K, t + 2, Bn, 0, tid);
        if (q == 2) stageB_third(Btile, K, t + 2, Bn, 1, tid);
        if (q == 3) {
          stageA_half(Atile, K, t + 2, An, 1, tid);
          stageB_third(Btile, K, t + 2, Bn, 2, tid);
          stageB_third(Btile, K, t + 2, Bn, 3, tid);
        }
      }
      asm volatile("s_barrier" ::: "memory");
      __builtin_amdgcn_s_setprio(1);
#pragma unroll
      for (int dm = 0; dm < 2; dm++)
#pragma unroll
        for (int nf = 0; nf < 4; nf++)
#pragma unroll
          for (int ks = 0; ks < 2; ks++)
            acc[q * 2 + dm][nf] = __builtin_amdgcn_mfma_f32_16x16x32_bf16(
                afr[dm][ks], bfrag[nf][ks], acc[q * 2 + dm][nf], 0, 0, 0);
      __builtin_amdgcn_s_setprio(0);
      if (q < 3) {
        asm volatile("s_barrier" ::: "memory");
      } else {
        if (st) asm volatile("s_waitcnt vmcnt(8)" ::: "memory");
        else    asm volatile("s_waitcnt vmcnt(0)" ::: "memory");
        asm volatile("s_barrier" ::: "memory");
      }
    }
  }

#pragma unroll
  for (int mf = 0; mf < 8; mf++)
#pragma unroll
    for (int nf = 0; nf < 4; nf++)
#pragma unroll
      for (int r = 0; r < 4; r++) {
        int m = m0 + wm * 128 + mf * 16 + l4 * 4 + r;
        int n = n0 + wn * 64 + nf * 16 + l15;
        C[(size_t)m * N + n] = acc[mf][nf][r];
      }
}

// K tile stage (shared across 8 waves, 2 DMA lines per thread)
__device__ __forceinline__ void stage_k8(const ushort* Kt, ushort* Ks, int tid) {
  int l = tid & 63, w = tid >> 6;
#pragma unroll
  for (int n = 0; n < 2; n++) {
    int cidx = w * 2 + n;
    int r = cidx * 4 + (l >> 4);
    int cs = ((l & 15) * 8) ^ ((r & 7) << 3);
    gld16(Kt + (size_t)r * 3072 + cs, Ks + cidx * 512 + l * 8);
  }
}

__device__ __forceinline__ void stage_v8(const ushort* Vt, ushort* Vs, int tid) {
  int l = tid & 63, w = tid >> 6;
#pragma unroll
  for (int n = 0; n < 2; n++) {
    int cidx = w * 2 + n;
    int d = cidx * 8 + (l >> 3);
    int cs = ((l & 7) * 8) ^ ((d & 7) << 3);
    gld16(Vt + (size_t)d * 2048 + cs, Vs + cidx * 512 + l * 8);
  }
}

// ---------------- causal GQA flash attention: 8-wave blocks, shared K/V LDS ------
// R16/R18/R19 structure + T5 setprio around QK and PV MFMA clusters (single new
// variable this round; attn waves have role diversity: masked waves stage-only
// while others compute -> catalog m191-positive regime).
__global__ __launch_bounds__(512) void k_attn(const ushort* __restrict__ QKV,
                                              const ushort* __restrict__ VT,
                                              ushort* __restrict__ O) {
  const int T = 2048, HD = 128, G = 4, H = 16, RS = 3072;
  const float SCALE2 = 0.08838834764831845f * 1.4426950408889634f;
  const float MFIX = 12.0f;
  int bid = blockIdx.x;
  int pr = bid >> 6;
  int bh = bid & 63;
  int h = bh & 15, b = bh >> 4;
  int g = h & 3;
  int tid = threadIdx.x, wid = tid >> 6, lane = tid & 63;
  int l15 = lane & 15, l4 = lane >> 4;
  int kswz = (l15 & 7) << 3;

  __shared__ __align__(16) char smem[102400];
  ushort* Ks0 = (ushort*)smem;
  ushort* Ks1 = (ushort*)(smem + 16384);
  ushort* Vs0 = (ushort*)(smem + 32768);
  ushort* Vs1 = (ushort*)(smem + 49152);
  ushort* Pw  = (ushort*)(smem + 65536) + wid * (32 * 72);

  const ushort* Qb = &QKV[(size_t)b * T * RS + h * HD];
  const ushort* Kb = &QKV[(size_t)b * T * RS + 2048 + g * HD];
  const ushort* Vb = &VT[((size_t)b * G + g) * (size_t)HD * T];

#pragma unroll 1
  for (int half = 0; half < 2; half++) {
    int ch = half ? pr : (7 - pr);
    int qw = ch * 256 + wid * 32;
    int nt = 4 * (ch + 1);

    short8 qf[2][4];
#pragma unroll
    for (int mf = 0; mf < 2; mf++)
#pragma unroll
      for (int kf = 0; kf < 4; kf++)
        qf[mf][kf] = *(const short8*)&Qb[(size_t)(qw + mf * 16 + l15) * RS + kf * 32 + l4 * 8];

    f32x4 o[2][8] = {};
    float lrow[8];
#pragma unroll
    for (int i = 0; i < 8; i++) lrow[i] = 0.f;

    stage_k8(Kb, Ks0, tid);
    stage_v8(Vb, Vs0, tid);
    __syncthreads();

#pragma unroll 1
    for (int it = 0; it < nt; ++it) {
      int t0 = it * 64;
      int cur = it & 1;
      ushort* Kc = cur ? Ks1 : Ks0;
      ushort* Vc = cur ? Vs1 : Vs0;
      if (it + 1 < nt) {
        stage_k8(Kb + (size_t)(t0 + 64) * RS, cur ? Ks0 : Ks1, tid);
        stage_v8(Vb + t0 + 64, cur ? Vs0 : Vs1, tid);
      }
      if (t0 <= qw + 31) {
        f32x4 s[2][4] = {};
        __builtin_amdgcn_s_setprio(1);
#pragma unroll
        for (int kf = 0; kf < 4; kf++) {
#pragma unroll
          for (int nf = 0; nf < 4; nf++) {
            short8 bk = *(const short8*)&Kc[(nf * 16 + l15) * 128 + ((kf * 32 + l4 * 8) ^ kswz)];
            s[0][nf] = __builtin_amdgcn_mfma_f32_16x16x32_bf16(qf[0][kf], bk, s[0][nf], 0, 0, 0);
            s[1][nf] = __builtin_amdgcn_mfma_f32_16x16x32_bf16(qf[1][kf], bk, s[1][nf], 0, 0, 0);
          }
        }
        __builtin_amdgcn_s_setprio(0);
        bool needmask = (t0 + 63 > qw);
        if (needmask) {
#pragma unroll
          for (int mf = 0; mf < 2; mf++)
#pragma unroll
            for (int nf = 0; nf < 4; nf++)
#pragma unroll
              for (int r = 0; r < 4; r++) {
                int qq = qw + mf * 16 + l4 * 4 + r;
                int kk = t0 + nf * 16 + l15;
                if (kk > qq) s[mf][nf][r] = -1e30f;
              }
        }
        float rs[8];
#pragma unroll
        for (int i = 0; i < 8; i++) rs[i] = 0.f;
#pragma unroll
        for (int mf = 0; mf < 2; mf++)
#pragma unroll
          for (int nf = 0; nf < 4; nf++)
#pragma unroll
            for (int r = 0; r < 4; r++) {
              float pq = fexp2(__builtin_fmaf(s[mf][nf][r], SCALE2, -MFIX));
              rs[mf * 4 + r] += pq;
              Pw[(mf * 16 + l4 * 4 + r) * 72 + nf * 16 + l15] = f2bf_trunc(pq);
            }
#pragma unroll
        for (int i = 0; i < 8; i++) lrow[i] += rs[i];
        __builtin_amdgcn_s_setprio(1);
#pragma unroll
        for (int kf = 0; kf < 2; kf++) {
          short8 pa0 = *(const short8*)&Pw[(l15) * 72 + kf * 32 + l4 * 8];
          short8 pa1 = *(const short8*)&Pw[(16 + l15) * 72 + kf * 32 + l4 * 8];
#pragma unroll
          for (int nfo = 0; nfo < 8; nfo++) {
            short8 bv = *(const short8*)&Vc[(nfo * 16 + l15) * 64 + ((kf * 32 + l4 * 8) ^ kswz)];
            o[0][nfo] = __builtin_amdgcn_mfma_f32_16x16x32_bf16(pa0, bv, o[0][nfo], 0, 0, 0);
            o[1][nfo] = __builtin_amdgcn_mfma_f32_16x16x32_bf16(pa1, bv, o[1][nfo], 0, 0, 0);
          }
        }
        __builtin_amdgcn_s_setprio(0);
      }
      __syncthreads();
    }

#pragma unroll
    for (int i = 0; i < 8; i++) {
      float x = lrow[i];
      x += __shfl_xor(x, 1);
      x += __shfl_xor(x, 2);
      x += __shfl_xor(x, 4);
      x += __shfl_xor(x, 8);
      lrow[i] = x;
    }
    float inv[8];
#pragma unroll
    for (int i = 0; i < 8; i++) inv[i] = 1.0f / lrow[i];
#pragma unroll
    for (int mf = 0; mf < 2; mf++)
#pragma unroll
      for (int nfo = 0; nfo < 8; nfo++)
#pragma unroll
        for (int r = 0; r < 4; r++) {
          int t = qw + mf * 16 + l4 * 4 + r;
          int d = nfo * 16 + l15;
          O[(((size_t)b * T + t) * H + h) * HD + d] = f2bf(o[mf][nfo][r] * inv[mf * 4 + r]);
        }
    __syncthreads();
  }
}

extern "C" void kernel_launch(void* const* d_in, const int* in_sizes, int n_in,
                              void* d_out, int out_size, void* d_ws, size_t ws_size,
                              hipStream_t stream) {
  const float* x   = (const float*)d_in[0];
  const float* w_q = (const float*)d_in[1];
  const float* w_k = (const float*)d_in[2];
  const float* w_v = (const float*)d_in[3];
  const float* w_o = (const float*)d_in[4];

  char* ws = (char*)d_ws;
  ushort* xbf  = (ushort*)(ws);                // 32MB (reused as attn out)
  ushort* wkvT = (ushort*)(ws + 33554432ul);   // 12MB: [wq|wk|wv]^T = [3072,2048]
  ushort* woT  = (ushort*)(ws + 46137344ul);   // 8MB
  ushort* qkvb = (ushort*)(ws + 54525952ul);   // 48MB: (B,T,3072)
  ushort* VTb  = (ushort*)(ws + 104857600ul);  // 8MB  (total 113,246,208 B)
  ushort* attn = xbf;

  k_f32_to_bf16<<<8192, 256, 0, stream>>>(x, xbf, 16777216L);
  k_w_transpose<<<dim3(64, 64), 256, 0, stream>>>(w_q, wkvT, 2048, 2048);
  k_w_transpose<<<dim3(16, 64), 256, 0, stream>>>(w_k, wkvT + 2048ul * 2048, 2048, 512);
  k_w_transpose<<<dim3(16, 64), 256, 0, stream>>>(w_v, wkvT + 2560ul * 2048, 2048, 512);
  k_w_transpose<<<dim3(64, 64), 256, 0, stream>>>(w_o, woT, 2048, 2048);

  // QKV: 256x192 tiles, 4-phase pipelined -> 512 blocks = 2 full rounds
  k_gemm192p<<<dim3(16, 32), 512, 0, stream>>>(xbf, wkvT, qkvb, 8192, 3072, 2048);

  k_v_transpose<<<dim3(64, 4, 16), 256, 0, stream>>>(qkvb, VTb);

  k_attn<<<256, 512, 0, stream>>>(qkvb, VTb, attn);

  // WO: 256x256, 4-phase pipelined (160KB LDS) -> 256 blocks = 1 full round
  k_gemm256p4<<<dim3(8, 32), 512, 0, stream>>>(attn, woT, (float*)d_out, 8192, 2048, 2048);
}

// Round 21
// 300.395 us; speedup vs baseline: 1.0075x; 1.0075x over previous
//
#include <hip/hip_runtime.h>
#include <stdint.h>

typedef __attribute__((ext_vector_type(8))) short short8;
typedef __attribute__((ext_vector_type(8))) unsigned short ushort8;
typedef __attribute__((ext_vector_type(4))) float f32x4;

__device__ __forceinline__ ushort f2bf(float f) {
  union { float f; uint32_t u; } v; v.f = f;
  uint32_t r = v.u + 0x7FFFu + ((v.u >> 16) & 1u);
  return (ushort)(r >> 16);
}

__device__ __forceinline__ ushort f2bf_trunc(float f) {  // round-to-zero, 1 op
  union { float f; uint32_t u; } v; v.f = f;
  return (ushort)(v.u >> 16);
}

__device__ __forceinline__ float fexp2(float x) {  // 2^x, single v_exp_f32
  float r;
  asm("v_exp_f32 %0, %1" : "=v"(r) : "v"(x));
  return r;
}

__device__ __forceinline__ void gld16(const ushort* g, ushort* l) {
  __builtin_amdgcn_global_load_lds((const __attribute__((address_space(1))) void*)g,
                                   (__attribute__((address_space(3))) void*)l, 16, 0, 0);
}

// ---------------- fp32 -> bf16 elementwise ----------------
__global__ __launch_bounds__(256) void k_f32_to_bf16(const float* __restrict__ in,
                                                     ushort* __restrict__ out, long n) {
  long i = ((long)blockIdx.x * 256 + threadIdx.x) * 8;
  if (i >= n) return;
  float4 a = *(const float4*)(in + i);
  float4 b = *(const float4*)(in + i + 4);
  ushort8 o;
  o[0] = f2bf(a.x); o[1] = f2bf(a.y); o[2] = f2bf(a.z); o[3] = f2bf(a.w);
  o[4] = f2bf(b.x); o[5] = f2bf(b.y); o[6] = f2bf(b.z); o[7] = f2bf(b.w);
  *(ushort8*)(out + i) = o;
}

// ---------------- fp32 (R x C) -> bf16 transposed (C x R), out row-stride R ----------------
__global__ __launch_bounds__(256) void k_w_transpose(const float* __restrict__ in,
                                                     ushort* __restrict__ out, int R, int C) {
  __shared__ float t[32][33];
  int tx = threadIdx.x & 31, ty = threadIdx.x >> 5;
  int r0 = blockIdx.y * 32, c0 = blockIdx.x * 32;
#pragma unroll
  for (int i = 0; i < 4; i++)
    t[ty + i * 8][tx] = in[(size_t)(r0 + ty + i * 8) * C + c0 + tx];
  __syncthreads();
#pragma unroll
  for (int i = 0; i < 4; i++)
    out[(size_t)(c0 + ty + i * 8) * R + r0 + tx] = f2bf(t[tx][ty + i * 8]);
}

// ---------------- V slice of QKV (B,T,3072) -> VT (B,G,HD,T) bf16 ----------------
__global__ __launch_bounds__(256) void k_v_transpose(const ushort* __restrict__ qkv,
                                                     ushort* __restrict__ out) {
  __shared__ ushort t[32][33];
  int tx = threadIdx.x & 31, ty = threadIdx.x >> 5;
  int t0 = blockIdx.x * 32, d0 = blockIdx.y * 32;
  int b = blockIdx.z >> 2, g = blockIdx.z & 3;
#pragma unroll
  for (int i = 0; i < 4; i++)
    t[ty + i * 8][tx] =
        qkv[((size_t)b * 2048 + t0 + ty + i * 8) * 3072 + 2560 + g * 128 + d0 + tx];
  __syncthreads();
#pragma unroll
  for (int i = 0; i < 4; i++)
    out[(((size_t)b * 4 + g) * 128 + d0 + ty + i * 8) * 2048 + t0 + tx] = t[tx][ty + i * 8];
}

// A-half h (128 rows, 16KB) of K-tile t -> slot; 2 gld16/thread.
__device__ __forceinline__ void stageA_half(const ushort* Atile, int K, int t,
                                            ushort* slot, int h, int tid) {
#pragma unroll
  for (int n = 0; n < 2; n++) {
    int row = h * 128 + n * 64 + (tid >> 3);
    int c0 = (tid & 7) * 8;
    int cs = c0 ^ ((row & 7) << 3);
    gld16(Atile + (size_t)row * K + t * 64 + cs, slot + row * 64 + c0);
  }
}

// B chunk bq (64 rows, 8KB) of K-tile t -> slot; 1 gld16/thread.
__device__ __forceinline__ void stageB_third(const ushort* Btile, int K, int t,
                                             ushort* slot, int b, int tid) {
  int row = b * 64 + (tid >> 3);
  int c0 = (tid & 7) * 8;
  int cs = c0 ^ ((row & 7) << 3);
  gld16(Btile + (size_t)row * K + t * 64 + cs, slot + row * 64 + c0);
}

// ---------------- QKV GEMM: 256x192, BK=64, 4-phase pipelined ----------
// (verified 120.5us, 512 blocks = 2 full rounds)
__global__ __launch_bounds__(512) void k_gemm192p(const ushort* __restrict__ A,
                                                  const ushort* __restrict__ BT,
                                                  ushort* __restrict__ C, int M, int N, int K) {
  __shared__ ushort As[3][16384];  // 3 x 256x64
  __shared__ ushort Bs[2][12288];  // 2 x 192x64
  const int tid = threadIdx.x;
  const int lane = tid & 63, wid = tid >> 6;
  const int wm = wid >> 2, wn = wid & 3;
  const int l15 = lane & 15, l4 = lane >> 4;
  const int rsw = (l15 & 7) << 3;
  int nwg = gridDim.x * gridDim.y;
  int lin = blockIdx.y * gridDim.x + blockIdx.x;
  int swz = (lin & 7) * (nwg >> 3) + (lin >> 3);
  int bx = swz % gridDim.x, by = swz / gridDim.x;
  const int m0 = by * 256, n0 = bx * 192;
  const ushort* Atile = A + (size_t)m0 * K;
  const ushort* Btile = BT + (size_t)n0 * K;
  const int NK = K >> 6;

  f32x4 acc[8][3] = {};

  stageA_half(Atile, K, 0, As[0], 0, tid);
  stageA_half(Atile, K, 0, As[0], 1, tid);
  stageB_third(Btile, K, 0, Bs[0], 0, tid);
  stageB_third(Btile, K, 0, Bs[0], 1, tid);
  stageB_third(Btile, K, 0, Bs[0], 2, tid);
  stageA_half(Atile, K, 1, As[1], 0, tid);
  stageA_half(Atile, K, 1, As[1], 1, tid);
  stageB_third(Btile, K, 1, Bs[1], 0, tid);
  stageB_third(Btile, K, 1, Bs[1], 1, tid);
  stageB_third(Btile, K, 1, Bs[1], 2, tid);
  asm volatile("s_waitcnt vmcnt(7)" ::: "memory");
  asm volatile("s_barrier" ::: "memory");

#pragma unroll 1
  for (int t = 0; t < NK; ++t) {
    const ushort* Ab = As[t % 3];
    const ushort* Bb = Bs[t & 1];
    ushort* An = As[(t + 2) % 3];
    ushort* Bn = Bs[t & 1];
    const bool st = (t + 2 < NK);
    short8 bfrag[3][2];

#pragma unroll
    for (int nf = 0; nf < 3; nf++)
#pragma unroll
      for (int ks = 0; ks < 2; ks++)
        bfrag[nf][ks] = *(const short8*)&Bb[(wn * 48 + nf * 16 + l15) * 64 +
                                            ((ks * 32 + l4 * 8) ^ rsw)];
    {
      short8 afr[2][2];
#pragma unroll
      for (int dm = 0; dm < 2; dm++)
#pragma unroll
        for (int ks = 0; ks < 2; ks++)
          afr[dm][ks] = *(const short8*)&Ab[(wm * 128 + dm * 16 + l15) * 64 +
                                            ((ks * 32 + l4 * 8) ^ rsw)];
      if (st) stageA_half(Atile, K, t + 2, An, 0, tid);
      asm volatile("s_barrier" ::: "memory");
      __builtin_amdgcn_s_setprio(1);
#pragma unroll
      for (int dm = 0; dm < 2; dm++)
#pragma unroll
        for (int nf = 0; nf < 3; nf++)
#pragma unroll
          for (int ks = 0; ks < 2; ks++)
            acc[dm][nf] = __builtin_amdgcn_mfma_f32_16x16x32_bf16(
                afr[dm][ks], bfrag[nf][ks], acc[dm][nf], 0, 0, 0);
      __builtin_amdgcn_s_setprio(0);
      asm volatile("s_barrier" ::: "memory");
    }
#pragma unroll
    for (int q = 1; q < 4; q++) {
      short8 afr[2][2];
#pragma unroll
      for (int dm = 0; dm < 2; dm++)
#pragma unroll
        for (int ks = 0; ks < 2; ks++)
          afr[dm][ks] = *(const short8*)&Ab[(wm * 128 + (q * 2 + dm) * 16 + l15) * 64 +
                                            ((ks * 32 + l4 * 8) ^ rsw)];
      if (st) {
        if (q == 1) stageB_third(Btile, K, t + 2, Bn, 0, tid);
        if (q == 2) stageB_third(Btile, K, t + 2, Bn, 1, tid);
        if (q == 3) {
          stageA_half(Atile, K, t + 2, An, 1, tid);
          stageB_third(Btile, K, t + 2, Bn, 2, tid);
        }
      }
      asm volatile("s_barrier" ::: "memory");
      __builtin_amdgcn_s_setprio(1);
#pragma unroll
      for (int dm = 0; dm < 2; dm++)
#pragma unroll
        for (int nf = 0; nf < 3; nf++)
#pragma unroll
          for (int ks = 0; ks < 2; ks++)
            acc[q * 2 + dm][nf] = __builtin_amdgcn_mfma_f32_16x16x32_bf16(
                afr[dm][ks], bfrag[nf][ks], acc[q * 2 + dm][nf], 0, 0, 0);
      __builtin_amdgcn_s_setprio(0);
      if (q < 3) {
        asm volatile("s_barrier" ::: "memory");
      } else {
        if (st) asm volatile("s_waitcnt vmcnt(7)" ::: "memory");
        else    asm volatile("s_waitcnt vmcnt(0)" ::: "memory");
        asm volatile("s_barrier" ::: "memory");
      }
    }
  }

#pragma unroll
  for (int mf = 0; mf < 8; mf++)
#pragma unroll
    for (int nf = 0; nf < 3; nf++)
#pragma unroll
      for (int r = 0; r < 4; r++) {
        int m = m0 + wm * 128 + mf * 16 + l4 * 4 + r;
        int n = n0 + wn * 48 + nf * 16 + l15;
        C[(size_t)m * N + n] = f2bf(acc[mf][nf][r]);
      }
}

// ---------------- WO GEMM: 256x256, BK=64, 4-phase pipelined ----------
// (verified ~67us, 160KB LDS, 256 blocks = 1 full round)
__global__ __launch_bounds__(512) void k_gemm256p4(const ushort* __restrict__ A,
                                                   const ushort* __restrict__ BT,
                                                   float* __restrict__ C, int M, int N, int K) {
  __shared__ ushort As[3][16384];  // 3 x 256x64 = 96KB
  __shared__ ushort Bs[2][16384];  // 2 x 256x64 = 64KB
  const int tid = threadIdx.x;
  const int lane = tid & 63, wid = tid >> 6;
  const int wm = wid >> 2, wn = wid & 3;
  const int l15 = lane & 15, l4 = lane >> 4;
  const int rsw = (l15 & 7) << 3;
  int nwg = gridDim.x * gridDim.y;
  int lin = blockIdx.y * gridDim.x + blockIdx.x;
  int swz = (lin & 7) * (nwg >> 3) + (lin >> 3);
  int bx = swz % gridDim.x, by = swz / gridDim.x;
  const int m0 = by * 256, n0 = bx * 256;
  const ushort* Atile = A + (size_t)m0 * K;
  const ushort* Btile = BT + (size_t)n0 * K;
  const int NK = K >> 6;

  f32x4 acc[8][4] = {};

  stageA_half(Atile, K, 0, As[0], 0, tid);
  stageA_half(Atile, K, 0, As[0], 1, tid);
  stageB_third(Btile, K, 0, Bs[0], 0, tid);
  stageB_third(Btile, K, 0, Bs[0], 1, tid);
  stageB_third(Btile, K, 0, Bs[0], 2, tid);
  stageB_third(Btile, K, 0, Bs[0], 3, tid);
  stageA_half(Atile, K, 1, As[1], 0, tid);
  stageA_half(Atile, K, 1, As[1], 1, tid);
  stageB_third(Btile, K, 1, Bs[1], 0, tid);
  stageB_third(Btile, K, 1, Bs[1], 1, tid);
  stageB_third(Btile, K, 1, Bs[1], 2, tid);
  stageB_third(Btile, K, 1, Bs[1], 3, tid);
  asm volatile("s_waitcnt vmcnt(8)" ::: "memory");
  asm volatile("s_barrier" ::: "memory");

#pragma unroll 1
  for (int t = 0; t < NK; ++t) {
    const ushort* Ab = As[t % 3];
    const ushort* Bb = Bs[t & 1];
    ushort* An = As[(t + 2) % 3];
    ushort* Bn = Bs[t & 1];
    const bool st = (t + 2 < NK);
    short8 bfrag[4][2];

#pragma unroll
    for (int nf = 0; nf < 4; nf++)
#pragma unroll
      for (int ks = 0; ks < 2; ks++)
        bfrag[nf][ks] = *(const short8*)&Bb[(wn * 64 + nf * 16 + l15) * 64 +
                                            ((ks * 32 + l4 * 8) ^ rsw)];
    {
      short8 afr[2][2];
#pragma unroll
      for (int dm = 0; dm < 2; dm++)
#pragma unroll
        for (int ks = 0; ks < 2; ks++)
          afr[dm][ks] = *(const short8*)&Ab[(wm * 128 + dm * 16 + l15) * 64 +
                                            ((ks * 32 + l4 * 8) ^ rsw)];
      if (st) stageA_half(Atile, K, t + 2, An, 0, tid);
      asm volatile("s_barrier" ::: "memory");
      __builtin_amdgcn_s_setprio(1);
#pragma unroll
      for (int dm = 0; dm < 2; dm++)
#pragma unroll
        for (int nf = 0; nf < 4; nf++)
#pragma unroll
          for (int ks = 0; ks < 2; ks++)
            acc[dm][nf] = __builtin_amdgcn_mfma_f32_16x16x32_bf16(
                afr[dm][ks], bfrag[nf][ks], acc[dm][nf], 0, 0, 0);
      __builtin_amdgcn_s_setprio(0);
      asm volatile("s_barrier" ::: "memory");
    }
#pragma unroll
    for (int q = 1; q < 4; q++) {
      short8 afr[2][2];
#pragma unroll
      for (int dm = 0; dm < 2; dm++)
#pragma unroll
        for (int ks = 0; ks < 2; ks++)
          afr[dm][ks] = *(const short8*)&Ab[(wm * 128 + (q * 2 + dm) * 16 + l15) * 64 +
                                            ((ks * 32 + l4 * 8) ^ rsw)];
      if (st) {
        if (q == 1) stageB_third(Btile, K, t + 2, Bn, 0, tid);
        if (q == 2) stageB_third(Btile, K, t + 2, Bn, 1, tid);
        if (q == 3) {
          stageA_half(Atile, K, t + 2, An, 1, tid);
          stageB_third(Btile, K, t + 2, Bn, 2, tid);
          stageB_third(Btile, K, t + 2, Bn, 3, tid);
        }
      }
      asm volatile("s_barrier" ::: "memory");
      __builtin_amdgcn_s_setprio(1);
#pragma unroll
      for (int dm = 0; dm < 2; dm++)
#pragma unroll
        for (int nf = 0; nf < 4; nf++)
#pragma unroll
          for (int ks = 0; ks < 2; ks++)
            acc[q * 2 + dm][nf] = __builtin_amdgcn_mfma_f32_16x16x32_bf16(
                afr[dm][ks], bfrag[nf][ks], acc[q * 2 + dm][nf], 0, 0, 0);
      __builtin_amdgcn_s_setprio(0);
      if (q < 3) {
        asm volatile("s_barrier" ::: "memory");
      } else {
        if (st) asm volatile("s_waitcnt vmcnt(8)" ::: "memory");
        else    asm volatile("s_waitcnt vmcnt(0)" ::: "memory");
        asm volatile("s_barrier" ::: "memory");
      }
    }
  }

#pragma unroll
  for (int mf = 0; mf < 8; mf++)
#pragma unroll
    for (int nf = 0; nf < 4; nf++)
#pragma unroll
      for (int r = 0; r < 4; r++) {
        int m = m0 + wm * 128 + mf * 16 + l4 * 4 + r;
        int n = n0 + wn * 64 + nf * 16 + l15;
        C[(size_t)m * N + n] = acc[mf][nf][r];
      }
}

// K tile stage (shared across 8 waves, 2 DMA lines per thread)
__device__ __forceinline__ void stage_k8(const ushort* Kt, ushort* Ks, int tid) {
  int l = tid & 63, w = tid >> 6;
#pragma unroll
  for (int n = 0; n < 2; n++) {
    int cidx = w * 2 + n;
    int r = cidx * 4 + (l >> 4);
    int cs = ((l & 15) * 8) ^ ((r & 7) << 3);
    gld16(Kt + (size_t)r * 3072 + cs, Ks + cidx * 512 + l * 8);
  }
}

__device__ __forceinline__ void stage_v8(const ushort* Vt, ushort* Vs, int tid) {
  int l = tid & 63, w = tid >> 6;
#pragma unroll
  for (int n = 0; n < 2; n++) {
    int cidx = w * 2 + n;
    int d = cidx * 8 + (l >> 3);
    int cs = ((l & 7) * 8) ^ ((d & 7) << 3);
    gld16(Vt + (size_t)d * 2048 + cs, Vs + cidx * 512 + l * 8);
  }
}

// ---------------- causal GQA flash attention: 8-wave blocks, shared K/V LDS ------
// (R19's verified version: dbuf K/V, fixed-m softmax, no setprio — R20's setprio
// was null-to-negative, consistent with m190's lockstep-structure null)
__global__ __launch_bounds__(512) void k_attn(const ushort* __restrict__ QKV,
                                              const ushort* __restrict__ VT,
                                              ushort* __restrict__ O) {
  const int T = 2048, HD = 128, G = 4, H = 16, RS = 3072;
  const float SCALE2 = 0.08838834764831845f * 1.4426950408889634f;
  const float MFIX = 12.0f;
  int bid = blockIdx.x;
  int pr = bid >> 6;
  int bh = bid & 63;
  int h = bh & 15, b = bh >> 4;
  int g = h & 3;
  int tid = threadIdx.x, wid = tid >> 6, lane = tid & 63;
  int l15 = lane & 15, l4 = lane >> 4;
  int kswz = (l15 & 7) << 3;

  __shared__ __align__(16) char smem[102400];
  ushort* Ks0 = (ushort*)smem;
  ushort* Ks1 = (ushort*)(smem + 16384);
  ushort* Vs0 = (ushort*)(smem + 32768);
  ushort* Vs1 = (ushort*)(smem + 49152);
  ushort* Pw  = (ushort*)(smem + 65536) + wid * (32 * 72);

  const ushort* Qb = &QKV[(size_t)b * T * RS + h * HD];
  const ushort* Kb = &QKV[(size_t)b * T * RS + 2048 + g * HD];
  const ushort* Vb = &VT[((size_t)b * G + g) * (size_t)HD * T];

#pragma unroll 1
  for (int half = 0; half < 2; half++) {
    int ch = half ? pr : (7 - pr);
    int qw = ch * 256 + wid * 32;
    int nt = 4 * (ch + 1);

    short8 qf[2][4];
#pragma unroll
    for (int mf = 0; mf < 2; mf++)
#pragma unroll
      for (int kf = 0; kf < 4; kf++)
        qf[mf][kf] = *(const short8*)&Qb[(size_t)(qw + mf * 16 + l15) * RS + kf * 32 + l4 * 8];

    f32x4 o[2][8] = {};
    float lrow[8];
#pragma unroll
    for (int i = 0; i < 8; i++) lrow[i] = 0.f;

    stage_k8(Kb, Ks0, tid);
    stage_v8(Vb, Vs0, tid);
    __syncthreads();

#pragma unroll 1
    for (int it = 0; it < nt; ++it) {
      int t0 = it * 64;
      int cur = it & 1;
      ushort* Kc = cur ? Ks1 : Ks0;
      ushort* Vc = cur ? Vs1 : Vs0;
      if (it + 1 < nt) {
        stage_k8(Kb + (size_t)(t0 + 64) * RS, cur ? Ks0 : Ks1, tid);
        stage_v8(Vb + t0 + 64, cur ? Vs0 : Vs1, tid);
      }
      if (t0 <= qw + 31) {
        f32x4 s[2][4] = {};
#pragma unroll
        for (int kf = 0; kf < 4; kf++) {
#pragma unroll
          for (int nf = 0; nf < 4; nf++) {
            short8 bk = *(const short8*)&Kc[(nf * 16 + l15) * 128 + ((kf * 32 + l4 * 8) ^ kswz)];
            s[0][nf] = __builtin_amdgcn_mfma_f32_16x16x32_bf16(qf[0][kf], bk, s[0][nf], 0, 0, 0);
            s[1][nf] = __builtin_amdgcn_mfma_f32_16x16x32_bf16(qf[1][kf], bk, s[1][nf], 0, 0, 0);
          }
        }
        bool needmask = (t0 + 63 > qw);
        if (needmask) {
#pragma unroll
          for (int mf = 0; mf < 2; mf++)
#pragma unroll
            for (int nf = 0; nf < 4; nf++)
#pragma unroll
              for (int r = 0; r < 4; r++) {
                int qq = qw + mf * 16 + l4 * 4 + r;
                int kk = t0 + nf * 16 + l15;
                if (kk > qq) s[mf][nf][r] = -1e30f;
              }
        }
        float rs[8];
#pragma unroll
        for (int i = 0; i < 8; i++) rs[i] = 0.f;
#pragma unroll
        for (int mf = 0; mf < 2; mf++)
#pragma unroll
          for (int nf = 0; nf < 4; nf++)
#pragma unroll
            for (int r = 0; r < 4; r++) {
              float pq = fexp2(__builtin_fmaf(s[mf][nf][r], SCALE2, -MFIX));
              rs[mf * 4 + r] += pq;
              Pw[(mf * 16 + l4 * 4 + r) * 72 + nf * 16 + l15] = f2bf_trunc(pq);
            }
#pragma unroll
        for (int i = 0; i < 8; i++) lrow[i] += rs[i];
#pragma unroll
        for (int kf = 0; kf < 2; kf++) {
          short8 pa0 = *(const short8*)&Pw[(l15) * 72 + kf * 32 + l4 * 8];
          short8 pa1 = *(const short8*)&Pw[(16 + l15) * 72 + kf * 32 + l4 * 8];
#pragma unroll
          for (int nfo = 0; nfo < 8; nfo++) {
            short8 bv = *(const short8*)&Vc[(nfo * 16 + l15) * 64 + ((kf * 32 + l4 * 8) ^ kswz)];
            o[0][nfo] = __builtin_amdgcn_mfma_f32_16x16x32_bf16(pa0, bv, o[0][nfo], 0, 0, 0);
            o[1][nfo] = __builtin_amdgcn_mfma_f32_16x16x32_bf16(pa1, bv, o[1][nfo], 0, 0, 0);
          }
        }
      }
      __syncthreads();
    }

#pragma unroll
    for (int i = 0; i < 8; i++) {
      float x = lrow[i];
      x += __shfl_xor(x, 1);
      x += __shfl_xor(x, 2);
      x += __shfl_xor(x, 4);
      x += __shfl_xor(x, 8);
      lrow[i] = x;
    }
    float inv[8];
#pragma unroll
    for (int i = 0; i < 8; i++) inv[i] = 1.0f / lrow[i];
#pragma unroll
    for (int mf = 0; mf < 2; mf++)
#pragma unroll
      for (int nfo = 0; nfo < 8; nfo++)
#pragma unroll
        for (int r = 0; r < 4; r++) {
          int t = qw + mf * 16 + l4 * 4 + r;
          int d = nfo * 16 + l15;
          O[(((size_t)b * T + t) * H + h) * HD + d] = f2bf(o[mf][nfo][r] * inv[mf * 4 + r]);
        }
    __syncthreads();
  }
}

extern "C" void kernel_launch(void* const* d_in, const int* in_sizes, int n_in,
                              void* d_out, int out_size, void* d_ws, size_t ws_size,
                              hipStream_t stream) {
  const float* x   = (const float*)d_in[0];
  const float* w_q = (const float*)d_in[1];
  const float* w_k = (const float*)d_in[2];
  const float* w_v = (const float*)d_in[3];
  const float* w_o = (const float*)d_in[4];

  char* ws = (char*)d_ws;
  ushort* xbf  = (ushort*)(ws);                // 32MB (reused as attn out)
  ushort* wkvT = (ushort*)(ws + 33554432ul);   // 12MB: [wq|wk|wv]^T = [3072,2048]
  ushort* woT  = (ushort*)(ws + 46137344ul);   // 8MB
  ushort* qkvb = (ushort*)(ws + 54525952ul);   // 48MB: (B,T,3072)
  ushort* VTb  = (ushort*)(ws + 104857600ul);  // 8MB  (total 113,246,208 B)
  ushort* attn = xbf;

  k_f32_to_bf16<<<8192, 256, 0, stream>>>(x, xbf, 16777216L);
  k_w_transpose<<<dim3(64, 64), 256, 0, stream>>>(w_q, wkvT, 2048, 2048);
  k_w_transpose<<<dim3(16, 64), 256, 0, stream>>>(w_k, wkvT + 2048ul * 2048, 2048, 512);
  k_w_transpose<<<dim3(16, 64), 256, 0, stream>>>(w_v, wkvT + 2560ul * 2048, 2048, 512);
  k_w_transpose<<<dim3(64, 64), 256, 0, stream>>>(w_o, woT, 2048, 2048);

  // QKV: 256x192 tiles, 4-phase pipelined -> 512 blocks = 2 full rounds
  k_gemm192p<<<dim3(16, 32), 512, 0, stream>>>(xbf, wkvT, qkvb, 8192, 3072, 2048);

  k_v_transpose<<<dim3(64, 4, 16), 256, 0, stream>>>(qkvb, VTb);

  k_attn<<<256, 512, 0, stream>>>(qkvb, VTb, attn);

  // WO: 256x256, 4-phase pipelined (160KB LDS) -> 256 blocks = 1 full round
  k_gemm256p4<<<dim3(8, 32), 512, 0, stream>>>(attn, woT, (float*)d_out, 8192, 2048, 2048);
}